// Round 13
// baseline (93.886 us; speedup 1.0000x reference)
//
#include <hip/hip_runtime.h>

#define DIM   64
#define NROWS 65536
#define NCODE 1024
#define RPB   256
#define NBLK  (NROWS / RPB)   // 256 blocks x 1024 thr (16 waves) -> 1 block/CU

typedef float    f32x4 __attribute__((ext_vector_type(4)));
typedef _Float16 f16x8 __attribute__((ext_vector_type(8)));

union U4H { uint4 u; f16x8 h; };

// fp32 = h + r, h = RNE fp16; r exact (Sterbenz); l = RNE fp16 of r.
__device__ __forceinline__ void split2(float f, unsigned short& hb,
                                       unsigned short& lb) {
  _Float16 h = (_Float16)f;
  float r = f - (float)h;
  _Float16 lo = (_Float16)r;
  hb = __builtin_bit_cast(unsigned short, h);
  lb = __builtin_bit_cast(unsigned short, lo);
}
__device__ __forceinline__ uint4 pack8(const unsigned short* p) {
  return make_uint4((unsigned)p[0] | ((unsigned)p[1] << 16),
                    (unsigned)p[2] | ((unsigned)p[3] << 16),
                    (unsigned)p[4] | ((unsigned)p[5] << 16),
                    (unsigned)p[6] | ((unsigned)p[7] << 16));
}

// ---- pre-pass: e -> fp16 (h,l) B-fragments + e2/2; also zeroes loss ----
// tile gt (16 codes): 4 frags [kh0_h, kh0_l, kh1_h, kh1_l] x 512 shorts,
// each frag lane-linear: lane l owns shorts [l*8, l*8+8).
__global__ __launch_bounds__(256) void vq_esplit(const float* __restrict__ e,
                                                 unsigned short* __restrict__ eB,
                                                 float* __restrict__ e2h,
                                                 float* __restrict__ loss) {
  const int c = blockIdx.x * 256 + threadIdx.x;   // code 0..1023
  if (c == 0) *loss = 0.f;                        // stream-ordered before vq_main
  const int gt = c >> 4, cl = c & 15;
  float s = 0.f;
  #pragma unroll
  for (int kh = 0; kh < 2; ++kh) {
    #pragma unroll
    for (int g = 0; g < 4; ++g) {
      const float* ep = e + (size_t)c * DIM + kh * 32 + g * 8;
      float4 v0 = *(const float4*)ep;
      float4 v1 = *(const float4*)(ep + 4);
      float f[8] = {v0.x, v0.y, v0.z, v0.w, v1.x, v1.y, v1.z, v1.w};
      unsigned short hb[8], lb[8];
      #pragma unroll
      for (int j = 0; j < 8; ++j) {
        split2(f[j], hb[j], lb[j]);
        s = fmaf(f[j], f[j], s);
      }
      const size_t pos = (size_t)((g << 4) | cl) * 8;
      const size_t tb = (size_t)gt * 2048;
      *(uint4*)(eB + tb + (kh * 2 + 0) * 512 + pos) = pack8(hb);
      *(uint4*)(eB + tb + (kh * 2 + 1) * 512 + pos) = pack8(lb);
    }
  }
  e2h[c] = 0.5f * s;
}

// one 16B-per-lane async global->LDS copy (1 KB per wave-instruction)
__device__ __forceinline__ void load_lds16(const void* gsrc, void* ldst) {
  __builtin_amdgcn_global_load_lds(
      (const __attribute__((address_space(1))) unsigned int*)
          (unsigned long long)gsrc,
      (__attribute__((address_space(3))) unsigned int*)
          (unsigned long long)ldst,
      16, 0, 0);
}

// ---- main: codebook REGISTER-RESIDENT (wave wv owns codes [wv*64,wv*64+64)
// as 16 uint4 B-frags), x STREAMED: 16 batches x 16 rows via LDS double
// buffer. Per batch per wave: 4 ds_read_b128 -> 24 MFMA. Candidates parked
// in LDS; single merge at end. ----
__global__ __launch_bounds__(1024, 4) void vq_main(
    const float* __restrict__ x,
    const float* __restrict__ e,
    const unsigned short* __restrict__ eB,
    const float* __restrict__ e2h,
    float* __restrict__ out,
    float* __restrict__ loss)
{
  __shared__ __align__(16) float xbuf[2][1024];   // 2 x 4 KB, chunk layout [kh][c][g][row]
  __shared__ float bestSL[16][RPB];               // 16 KB
  __shared__ int   bestKL[16][RPB];               // 16 KB
  __shared__ int   kFin[RPB];
  __shared__ float lossW[17];

  const int t   = threadIdx.x;
  const int l   = t & 63;
  const int wv  = t >> 6;        // 0..15
  const int col = l & 15;
  const int g   = l >> 4;
  const int B0  = blockIdx.x * RPB;

  // ---- prologue: this wave's 64-code B-frags -> 64 VGPRs, e2 -> 4 VGPRs ----
  uint4 bfr[16];
  {
    const unsigned short* ebw = eB + (size_t)(wv * 4) * 2048 + (size_t)l * 8;
    #pragma unroll
    for (int ct = 0; ct < 4; ++ct)
      #pragma unroll
      for (int q = 0; q < 4; ++q)
        bfr[ct * 4 + q] = *(const uint4*)(ebw + ct * 2048 + q * 512);
  }
  float e2v[4];
  #pragma unroll
  for (int ct = 0; ct < 4; ++ct) e2v[ct] = e2h[wv * 64 + ct * 16 + col];

  // staging: wave wv<4 handles chunk (kh,c)=(wv>>1,wv&1); 16B per lane.
  // LDS chunk layout: float idx = (kh*2+c)*256 + g*64 + row*4  (row=l&15)
  const float* xsrc = x + (size_t)(B0 + col) * DIM + (wv >> 1) * 32 + g * 8 + (wv & 1) * 4;

#define XSTAGE(M, B)                                                     \
  do { if (wv < 4)                                                       \
    load_lds16(xsrc + (size_t)(M) * (16 * DIM),                          \
               &xbuf[B][0] + wv * 256 + l * 4);                          \
  } while (0)

  XSTAGE(0, 0);
  asm volatile("s_waitcnt vmcnt(0)" ::: "memory");
  __builtin_amdgcn_s_barrier();
  __builtin_amdgcn_sched_barrier(0);

  float x2acc = 0.f;

#define BATCH(M, RB)                                                          \
  do {                                                                        \
    if ((M) < 15) XSTAGE((M) + 1, 1 - (RB));                                  \
    const float* xb = &xbuf[RB][0] + g * 64 + col * 4;                        \
    float4 x00 = *(const float4*)(xb + 0);                                    \
    float4 x01 = *(const float4*)(xb + 256);                                  \
    float4 x10 = *(const float4*)(xb + 512);                                  \
    float4 x11 = *(const float4*)(xb + 768);                                  \
    float xf[16] = {x00.x, x00.y, x00.z, x00.w, x01.x, x01.y, x01.z, x01.w,   \
                    x10.x, x10.y, x10.z, x10.w, x11.x, x11.y, x11.z, x11.w};  \
    unsigned short hb[16], lb[16];                                            \
    _Pragma("unroll")                                                         \
    for (int j = 0; j < 16; ++j) split2(xf[j], hb[j], lb[j]);                 \
    if (wv == 0) {                                                            \
      _Pragma("unroll")                                                       \
      for (int j = 0; j < 16; ++j) x2acc = fmaf(xf[j], xf[j], x2acc);         \
    }                                                                         \
    U4H ah0, ah1, al0, al1;                                                   \
    ah0.u = pack8(hb); ah1.u = pack8(hb + 8);                                 \
    al0.u = pack8(lb); al1.u = pack8(lb + 8);                                 \
    float bS[4]; int bK[4];                                                   \
    _Pragma("unroll")                                                         \
    for (int r = 0; r < 4; ++r) { bS[r] = -3.402823466e38f; bK[r] = 0; }      \
    _Pragma("unroll")                                                         \
    for (int ct = 0; ct < 4; ++ct) {                                          \
      U4H q0, q1, q2, q3;                                                     \
      q0.u = bfr[ct * 4 + 0]; q1.u = bfr[ct * 4 + 1];                         \
      q2.u = bfr[ct * 4 + 2]; q3.u = bfr[ct * 4 + 3];                         \
      const float ne2 = -e2v[ct];                                             \
      f32x4 c0 = {ne2, ne2, ne2, ne2};                                        \
      f32x4 c1 = {0.f, 0.f, 0.f, 0.f};                                        \
      c0 = __builtin_amdgcn_mfma_f32_16x16x32_f16(ah0.h, q0.h, c0, 0, 0, 0);  \
      c1 = __builtin_amdgcn_mfma_f32_16x16x32_f16(ah1.h, q2.h, c1, 0, 0, 0);  \
      c0 = __builtin_amdgcn_mfma_f32_16x16x32_f16(al0.h, q0.h, c0, 0, 0, 0);  \
      c1 = __builtin_amdgcn_mfma_f32_16x16x32_f16(al1.h, q2.h, c1, 0, 0, 0);  \
      c0 = __builtin_amdgcn_mfma_f32_16x16x32_f16(ah0.h, q1.h, c0, 0, 0, 0);  \
      c1 = __builtin_amdgcn_mfma_f32_16x16x32_f16(ah1.h, q3.h, c1, 0, 0, 0);  \
      const int kk = wv * 64 + ct * 16 + col;                                 \
      _Pragma("unroll")                                                       \
      for (int r = 0; r < 4; ++r) {                                           \
        float sv = c0[r] + c1[r];                                             \
        if (sv > bS[r]) { bS[r] = sv; bK[r] = kk; }                           \
      }                                                                       \
    }                                                                         \
    _Pragma("unroll")                                                         \
    for (int off = 1; off <= 8; off <<= 1) {                                  \
      _Pragma("unroll")                                                       \
      for (int r = 0; r < 4; ++r) {                                           \
        float sp = __shfl_xor(bS[r], off, 64);                                \
        int   kp = __shfl_xor(bK[r], off, 64);                                \
        if (sp > bS[r] || (sp == bS[r] && kp < bK[r])) {                      \
          bS[r] = sp; bK[r] = kp;                                             \
        }                                                                     \
      }                                                                       \
    }                                                                         \
    if (col == 0) {                                                           \
      _Pragma("unroll")                                                       \
      for (int r = 0; r < 4; ++r) {                                           \
        bestSL[wv][(M) * 16 + g * 4 + r] = bS[r];                             \
        bestKL[wv][(M) * 16 + g * 4 + r] = bK[r];                             \
      }                                                                       \
    }                                                                         \
    asm volatile("s_waitcnt vmcnt(0)" ::: "memory");                          \
    __builtin_amdgcn_s_barrier();                                             \
    __builtin_amdgcn_sched_barrier(0);                                        \
  } while (0)

  #pragma unroll 1
  for (int mm = 0; mm < 8; ++mm) {
    BATCH(2 * mm + 0, 0);
    BATCH(2 * mm + 1, 1);
  }

  // ---- single cross-wave merge: 4 threads/row over 16 candidate sets ----
  {
    const int row = t >> 2, q = t & 3;
    float s = bestSL[q * 4 + 0][row]; int k = bestKL[q * 4 + 0][row];
    #pragma unroll
    for (int j = 1; j < 4; ++j) {               // ascending wave (code) order
      float s2 = bestSL[q * 4 + j][row]; int k2 = bestKL[q * 4 + j][row];
      if (s2 > s || (s2 == s && k2 < k)) { s = s2; k = k2; }
    }
    #pragma unroll
    for (int off = 1; off <= 2; off <<= 1) {    // lexicographic across quads
      float s2 = __shfl_xor(s, off, 64);
      int   k2 = __shfl_xor(k, off, 64);
      if (s2 > s || (s2 == s && k2 < k)) { s = s2; k = k2; }
    }
    if (q == 0) kFin[row] = k;
    float sc = (q == 0) ? s : 0.f;
    #pragma unroll
    for (int off = 1; off < 64; off <<= 1) sc += __shfl_xor(sc, off, 64);
    if (l == 0) lossW[wv] = sc;                 // wave's 16-row Sum(S'best)
  }
  if (wv == 0) {
    float xs = x2acc;                           // wave 0 saw all 256 rows' x
    #pragma unroll
    for (int off = 1; off < 64; off <<= 1) xs += __shfl_xor(xs, off, 64);
    if (l == 0) lossW[16] = xs;
  }
  __syncthreads();
  if (t == 0) {
    float ss = 0.f;
    #pragma unroll
    for (int i = 0; i < 16; ++i) ss += lossW[i];
    atomicAdd(loss, fmaf(-2.f, ss, lossW[16]) * (1.25f / (float)((size_t)NROWS * DIM)));
  }

  // ---- cooperative gather-write of quantized rows (exact fp32 e copy) ----
  #pragma unroll
  for (int i = 0; i < 4; ++i) {
    const int id  = t + i * 1024;
    const int row = id >> 4, seg = id & 15;
    const int bk  = kFin[row];
    *(float4*)(out + (size_t)(B0 + row) * DIM + seg * 4) =
        *(const float4*)(e + (size_t)bk * DIM + seg * 4);
  }
}

extern "C" void kernel_launch(void* const* d_in, const int* in_sizes, int n_in,
                              void* d_out, int out_size, void* d_ws, size_t ws_size,
                              hipStream_t stream) {
  const float* x = (const float*)d_in[0];   // [65536, 64]
  const float* e = (const float*)d_in[1];   // [1024, 64]
  float* out  = (float*)d_out;              // quantized_st [65536*64] + loss [1]
  float* loss = out + (size_t)NROWS * DIM;

  unsigned short* eB = (unsigned short*)d_ws;            // 64 tiles * 4 KB = 256 KB
  float* e2h = (float*)((char*)d_ws + 64 * 2048 * 2);    // 4 KB

  vq_esplit<<<NCODE / 256, 256, 0, stream>>>(e, eB, e2h, loss);
  vq_main  <<<NBLK, 1024, 0, stream>>>(x, e, eB, e2h, out, loss);
}

// Round 14
// 60.605 us; speedup vs baseline: 1.5492x; 1.5492x over previous
//
#include <hip/hip_runtime.h>

#define DIM   64
#define NROWS 65536
#define NCODE 1024
#define RPB   128
#define NBLK  (NROWS / RPB)   // 512 blocks x 256 thr -> 2 blocks/CU, 16 waves/CU

typedef float    f32x4 __attribute__((ext_vector_type(4)));
typedef _Float16 f16x8 __attribute__((ext_vector_type(8)));

union U4H { uint4 u; f16x8 h; };

// fp32 = h + r, h = RNE fp16; r exact (Sterbenz); l = RNE fp16 of r.
__device__ __forceinline__ void split2(float f, unsigned short& hb,
                                       unsigned short& lb) {
  _Float16 h = (_Float16)f;
  float r = f - (float)h;
  _Float16 lo = (_Float16)r;
  hb = __builtin_bit_cast(unsigned short, h);
  lb = __builtin_bit_cast(unsigned short, lo);
}
__device__ __forceinline__ uint4 pack8(const unsigned short* p) {
  return make_uint4((unsigned)p[0] | ((unsigned)p[1] << 16),
                    (unsigned)p[2] | ((unsigned)p[3] << 16),
                    (unsigned)p[4] | ((unsigned)p[5] << 16),
                    (unsigned)p[6] | ((unsigned)p[7] << 16));
}

// ---- pre-pass: e -> fp16 (h,l) B-fragments + e2/2; also zeroes loss ----
// tile gt (16 codes): 4 frags [kh0_h, kh0_l, kh1_h, kh1_l] x 512 shorts,
// each frag lane-linear: lane l owns shorts [l*8, l*8+8).
__global__ __launch_bounds__(256) void vq_esplit(const float* __restrict__ e,
                                                 unsigned short* __restrict__ eB,
                                                 float* __restrict__ e2h,
                                                 float* __restrict__ loss) {
  const int c = blockIdx.x * 256 + threadIdx.x;   // code 0..1023
  if (c == 0) *loss = 0.f;                        // stream-ordered before vq_main
  const int gt = c >> 4, cl = c & 15;
  float s = 0.f;
  #pragma unroll
  for (int kh = 0; kh < 2; ++kh) {
    #pragma unroll
    for (int g = 0; g < 4; ++g) {
      const float* ep = e + (size_t)c * DIM + kh * 32 + g * 8;
      float4 v0 = *(const float4*)ep;
      float4 v1 = *(const float4*)(ep + 4);
      float f[8] = {v0.x, v0.y, v0.z, v0.w, v1.x, v1.y, v1.z, v1.w};
      unsigned short hb[8], lb[8];
      #pragma unroll
      for (int j = 0; j < 8; ++j) {
        split2(f[j], hb[j], lb[j]);
        s = fmaf(f[j], f[j], s);
      }
      const size_t pos = (size_t)((g << 4) | cl) * 8;
      const size_t tb = (size_t)gt * 2048;
      *(uint4*)(eB + tb + (kh * 2 + 0) * 512 + pos) = pack8(hb);
      *(uint4*)(eB + tb + (kh * 2 + 1) * 512 + pos) = pack8(lb);
    }
  }
  e2h[c] = 0.5f * s;
}

// ---- main: NO LDS staging, NO barriers in the loop. Wave = 32 rows x all
// 1024 codes; B-frags stream global->register (L2-resident, 1-tile rotate
// prefetch); per-wave phase rotation decorrelates the 2048 wave streams. ----
__global__ __launch_bounds__(256, 4) void vq_main(
    const float* __restrict__ x,
    const float* __restrict__ e,
    const unsigned short* __restrict__ eB,
    const float* __restrict__ e2h,
    float* __restrict__ out,
    float* __restrict__ loss)
{
  __shared__ __align__(16) float e2L[NCODE];   // 4 KB
  __shared__ int   kFin[RPB];
  __shared__ float lossP[4];

  const int t   = threadIdx.x;
  const int l   = t & 63;
  const int wv  = t >> 6;                    // 0..3
  const int col = l & 15;
  const int g   = l >> 4;
  const int B0  = blockIdx.x * RPB;
  const int R0  = B0 + wv * 32;              // this wave's 32 rows
  const int ph  = ((blockIdx.x * 4 + wv) * 23) & 63;   // per-WAVE phase

  // ---- x loads (8 independent float4) ----
  float4 xv[8];
  #pragma unroll
  for (int rt = 0; rt < 2; ++rt)
    #pragma unroll
    for (int kh = 0; kh < 2; ++kh) {
      const float* xp = x + (size_t)(R0 + rt * 16 + col) * DIM + kh * 32 + g * 8;
      xv[(rt * 2 + kh) * 2 + 0] = *(const float4*)xp;
      xv[(rt * 2 + kh) * 2 + 1] = *(const float4*)(xp + 4);
    }

  // ---- e2 -> LDS once (one barrier total, then barrier-free loop) ----
  #pragma unroll
  for (int i = 0; i < 4; ++i) e2L[t + i * 256] = e2h[t + i * 256];
  __syncthreads();

  // ---- split x -> fp16 (h,l) A-frags + Sum(x^2) over this wave's 32 rows ----
  f16x8 a[2][2][2];     // [row-tile][k-half][h/l]
  float x2p = 0.f;
  #pragma unroll
  for (int rt = 0; rt < 2; ++rt)
    #pragma unroll
    for (int kh = 0; kh < 2; ++kh) {
      float4 v0 = xv[(rt * 2 + kh) * 2], v1 = xv[(rt * 2 + kh) * 2 + 1];
      float f[8] = {v0.x, v0.y, v0.z, v0.w, v1.x, v1.y, v1.z, v1.w};
      unsigned short hb[8], lb[8];
      #pragma unroll
      for (int j = 0; j < 8; ++j) {
        split2(f[j], hb[j], lb[j]);
        x2p = fmaf(f[j], f[j], x2p);
      }
      U4H uh; uh.u = pack8(hb); a[rt][kh][0] = uh.h;
      U4H ul; ul.u = pack8(lb); a[rt][kh][1] = ul.h;
    }
  #pragma unroll
  for (int off = 1; off < 64; off <<= 1) x2p += __shfl_xor(x2p, off, 64);

  float bestS[2][4];
  int   bestK[2][4];
  #pragma unroll
  for (int rt = 0; rt < 2; ++rt)
    #pragma unroll
    for (int r = 0; r < 4; ++r) { bestS[rt][r] = -3.402823466e38f; bestK[rt][r] = 0; }

  // ---- prefetch tile ph into registers ----
  const unsigned short* ebl = eB + (size_t)l * 8;
  uint4 b0, b1, b2, b3;
  {
    const unsigned short* tp = ebl + (size_t)ph * 2048;
    b0 = *(const uint4*)(tp + 0 * 512);
    b1 = *(const uint4*)(tp + 1 * 512);
    b2 = *(const uint4*)(tp + 2 * 512);
    b3 = *(const uint4*)(tp + 3 * 512);
  }

  // ---- barrier-free main loop: rotate prefetch, 12 MFMA / tile ----
  #pragma unroll 4
  for (int m = 0; m < 64; ++m) {
    const int ptn = (ph + m + 1) & 63;       // last iter reloads ph: harmless
    const unsigned short* tn = ebl + (size_t)ptn * 2048;
    uint4 n0 = *(const uint4*)(tn + 0 * 512);
    uint4 n1 = *(const uint4*)(tn + 1 * 512);
    uint4 n2 = *(const uint4*)(tn + 2 * 512);
    uint4 n3 = *(const uint4*)(tn + 3 * 512);

    const int pt  = (ph + m) & 63;
    const int kk0 = pt * 16 + col;
    const float ne2 = -e2L[kk0];
    U4H q0, q1, q2, q3; q0.u = b0; q1.u = b1; q2.u = b2; q3.u = b3;
    #pragma unroll
    for (int rt = 0; rt < 2; ++rt) {
      f32x4 c0 = {ne2, ne2, ne2, ne2};
      f32x4 c1 = {0.f, 0.f, 0.f, 0.f};
      c0 = __builtin_amdgcn_mfma_f32_16x16x32_f16(a[rt][0][0], q0.h, c0, 0, 0, 0);
      c1 = __builtin_amdgcn_mfma_f32_16x16x32_f16(a[rt][1][0], q2.h, c1, 0, 0, 0);
      c0 = __builtin_amdgcn_mfma_f32_16x16x32_f16(a[rt][0][1], q0.h, c0, 0, 0, 0);
      c1 = __builtin_amdgcn_mfma_f32_16x16x32_f16(a[rt][1][1], q2.h, c1, 0, 0, 0);
      c0 = __builtin_amdgcn_mfma_f32_16x16x32_f16(a[rt][0][0], q1.h, c0, 0, 0, 0);
      c1 = __builtin_amdgcn_mfma_f32_16x16x32_f16(a[rt][1][0], q3.h, c1, 0, 0, 0);
      #pragma unroll
      for (int r = 0; r < 4; ++r) {
        float sv = c0[r] + c1[r];
        bool take = (sv > bestS[rt][r]) ||
                    (sv == bestS[rt][r] && kk0 < bestK[rt][r]);
        if (take) { bestS[rt][r] = sv; bestK[rt][r] = kk0; }
      }
    }
    b0 = n0; b1 = n1; b2 = n2; b3 = n3;
  }

  // ---- intra-wave argmax(S') merge over the 16 code-columns ----
  #pragma unroll
  for (int off = 1; off <= 8; off <<= 1) {
    #pragma unroll
    for (int rt = 0; rt < 2; ++rt)
      #pragma unroll
      for (int r = 0; r < 4; ++r) {
        float sp = __shfl_xor(bestS[rt][r], off, 64);
        int   kp = __shfl_xor(bestK[rt][r], off, 64);
        if (sp > bestS[rt][r] || (sp == bestS[rt][r] && kp < bestK[rt][r])) {
          bestS[rt][r] = sp; bestK[rt][r] = kp;
        }
      }
  }

  // col==0 lanes (g=0..3) hold FINAL minima for rows R0 + rt*16 + g*4 + r
  float ssum = 0.f;
  if (col == 0) {
    #pragma unroll
    for (int rt = 0; rt < 2; ++rt)
      #pragma unroll
      for (int r = 0; r < 4; ++r) {
        kFin[wv * 32 + rt * 16 + g * 4 + r] = bestK[rt][r];
        ssum += bestS[rt][r];
      }
  }
  ssum += __shfl_xor(ssum, 16, 64);
  ssum += __shfl_xor(ssum, 32, 64);
  if (l == 0)   // wave partial: Sum d(32 rows) = Sum x^2 - 2*Sum S'best
    lossP[wv] = fmaf(-2.f, ssum, x2p);

  __syncthreads();
  if (t == 0) {
    float bl = (lossP[0] + lossP[1]) + (lossP[2] + lossP[3]);
    atomicAdd(loss, bl * (1.25f / (float)((size_t)NROWS * DIM)));
  }

  // ---- cooperative gather-write: 2 threads/row, 32 floats each ----
  {
    const int row = t >> 1, half = t & 1;
    const int bk = kFin[row];
    const float4* src = (const float4*)(e + (size_t)bk * DIM + half * 32);
    float4* dst = (float4*)(out + (size_t)(B0 + row) * DIM + half * 32);
    #pragma unroll
    for (int i = 0; i < 8; ++i) dst[i] = src[i];
  }
}

extern "C" void kernel_launch(void* const* d_in, const int* in_sizes, int n_in,
                              void* d_out, int out_size, void* d_ws, size_t ws_size,
                              hipStream_t stream) {
  const float* x = (const float*)d_in[0];   // [65536, 64]
  const float* e = (const float*)d_in[1];   // [1024, 64]
  float* out  = (float*)d_out;              // quantized_st [65536*64] + loss [1]
  float* loss = out + (size_t)NROWS * DIM;

  unsigned short* eB = (unsigned short*)d_ws;            // 64 tiles * 4 KB = 256 KB
  float* e2h = (float*)((char*)d_ws + 64 * 2048 * 2);    // 4 KB

  vq_esplit<<<NCODE / 256, 256, 0, stream>>>(e, eB, e2h, loss);
  vq_main  <<<NBLK, 256, 0, stream>>>(x, e, eB, e2h, out, loss);
}

// Round 15
// 47.824 us; speedup vs baseline: 1.9632x; 1.2673x over previous
//
#include <hip/hip_runtime.h>

#define DIM   64
#define NROWS 65536
#define NCODE 1024
#define RPB   128
#define NBLK  (NROWS / RPB)   // 512 blocks x 512 thr -> 2 blocks/CU, 16 waves/CU

typedef float    f32x4 __attribute__((ext_vector_type(4)));
typedef _Float16 f16x8 __attribute__((ext_vector_type(8)));

union U4H { uint4 u; f16x8 h; };

// fp32 = h + r, h = RNE fp16; r exact (Sterbenz); l = RNE fp16 of r.
__device__ __forceinline__ void split2(float f, unsigned short& hb,
                                       unsigned short& lb) {
  _Float16 h = (_Float16)f;
  float r = f - (float)h;
  _Float16 lo = (_Float16)r;
  hb = __builtin_bit_cast(unsigned short, h);
  lb = __builtin_bit_cast(unsigned short, lo);
}
__device__ __forceinline__ uint4 pack8(const unsigned short* p) {
  return make_uint4((unsigned)p[0] | ((unsigned)p[1] << 16),
                    (unsigned)p[2] | ((unsigned)p[3] << 16),
                    (unsigned)p[4] | ((unsigned)p[5] << 16),
                    (unsigned)p[6] | ((unsigned)p[7] << 16));
}

// ---- pre-pass: e -> fp16 (h,l) B-fragments + e2/2; also zeroes loss ----
// tile gt (16 codes): 4 frags [kh0_h, kh0_l, kh1_h, kh1_l] x 512 shorts,
// each frag lane-linear: lane l owns shorts [l*8, l*8+8).
__global__ __launch_bounds__(256) void vq_esplit(const float* __restrict__ e,
                                                 unsigned short* __restrict__ eB,
                                                 float* __restrict__ e2h,
                                                 float* __restrict__ loss) {
  const int c = blockIdx.x * 256 + threadIdx.x;   // code 0..1023
  if (c == 0) *loss = 0.f;                        // stream-ordered before vq_main
  const int gt = c >> 4, cl = c & 15;
  float s = 0.f;
  #pragma unroll
  for (int kh = 0; kh < 2; ++kh) {
    #pragma unroll
    for (int g = 0; g < 4; ++g) {
      const float* ep = e + (size_t)c * DIM + kh * 32 + g * 8;
      float4 v0 = *(const float4*)ep;
      float4 v1 = *(const float4*)(ep + 4);
      float f[8] = {v0.x, v0.y, v0.z, v0.w, v1.x, v1.y, v1.z, v1.w};
      unsigned short hb[8], lb[8];
      #pragma unroll
      for (int j = 0; j < 8; ++j) {
        split2(f[j], hb[j], lb[j]);
        s = fmaf(f[j], f[j], s);
      }
      const size_t pos = (size_t)((g << 4) | cl) * 8;
      const size_t tb = (size_t)gt * 2048;
      *(uint4*)(eB + tb + (kh * 2 + 0) * 512 + pos) = pack8(hb);
      *(uint4*)(eB + tb + (kh * 2 + 1) * 512 + pos) = pack8(lb);
    }
  }
  e2h[c] = 0.5f * s;
}

// one 16B-per-lane async global->LDS copy (1 KB per wave-instruction)
__device__ __forceinline__ void load_lds16(const void* gsrc, void* ldst) {
  __builtin_amdgcn_global_load_lds(
      (const __attribute__((address_space(1))) unsigned int*)
          (unsigned long long)gsrc,
      (__attribute__((address_space(3))) unsigned int*)
          (unsigned long long)ldst,
      16, 0, 0);
}

// ---- main: 128 rows/block, 8 waves x 16 rows; all waves scan all 1024
// codes. Staging in 4-TILE GROUPS (16 KB) through a 3-slot ring: ONE
// barrier + ONE counted vmcnt per group -> 16 sync points total (vs 64). ----
__global__ __launch_bounds__(512) void vq_main(
    const float* __restrict__ x,
    const float* __restrict__ e,
    const unsigned short* __restrict__ eB,
    const float* __restrict__ e2h,
    float* __restrict__ out,
    float* __restrict__ loss)
{
  __shared__ __align__(16) unsigned short ring[3][4 * 2048]; // 48 KB, 3x16KB groups
  __shared__ __align__(16) float e2L[2048];                  // 8 KB (4 KB + stage pad)
  __shared__ int   kFin[RPB];
  __shared__ float lossP[8];

  const int t   = threadIdx.x;
  const int l   = t & 63;
  const int wv  = t >> 6;                    // 0..7
  const int col = l & 15;
  const int g   = l >> 4;
  const int B0  = blockIdx.x * RPB;
  const int R0  = B0 + wv * 16;              // this wave's 16 rows
  const int pg  = (blockIdx.x * 5) & 15;     // group-phase: decorrelate L2

  // ---- x loads first (oldest vmem; consumed in prologue) ----
  float4 xv[4];
  #pragma unroll
  for (int kh = 0; kh < 2; ++kh) {
    const float* xp = x + (size_t)(R0 + col) * DIM + kh * 32 + g * 8;
    xv[kh * 2 + 0] = *(const float4*)xp;
    xv[kh * 2 + 1] = *(const float4*)(xp + 4);
  }

  // group staging: wave wv stages tile (wv>>1) of the group, chunk pair
  // (wv&1): 2 x 1KB lane-linear copies. 8 waves cover 16 KB.
#define STAGEG(GIDX, SLOT)                                                    \
  do {                                                                        \
    const int gs_ = (pg + (GIDX)) & 15;                                       \
    const unsigned short* src_ = eB +                                         \
        ((size_t)gs_ * 4 + (wv >> 1)) * 2048 + (wv & 1) * 1024 + (size_t)l * 8; \
    unsigned short* dst_ =                                                    \
        &ring[SLOT][0] + (wv >> 1) * 2048 + (wv & 1) * 1024;                  \
    load_lds16(src_, dst_);                                                   \
    load_lds16(src_ + 512, dst_ + 512);                                       \
  } while (0)

  // e2 staged by all 8 waves (uniform vmcnt); waves 4-7 write the 4 KB pad.
  load_lds16(e2h + wv * 256 + l * 4, e2L + wv * 256);
  STAGEG(0, 0);
  STAGEG(1, 1);

  // ---- split x -> fp16 (h,l) A-frags + Sum(x^2) over this wave's 16 rows ----
  f16x8 a[2][2];     // [k-half][h/l]
  float x2p = 0.f;
  #pragma unroll
  for (int kh = 0; kh < 2; ++kh) {
    float4 v0 = xv[kh * 2], v1 = xv[kh * 2 + 1];
    float f[8] = {v0.x, v0.y, v0.z, v0.w, v1.x, v1.y, v1.z, v1.w};
    unsigned short hb[8], lb[8];
    #pragma unroll
    for (int j = 0; j < 8; ++j) {
      split2(f[j], hb[j], lb[j]);
      x2p = fmaf(f[j], f[j], x2p);
    }
    U4H uh; uh.u = pack8(hb); a[kh][0] = uh.h;
    U4H ul; ul.u = pack8(lb); a[kh][1] = ul.h;
  }
  #pragma unroll
  for (int off = 1; off < 64; off <<= 1) x2p += __shfl_xor(x2p, off, 64);

  float bestS[4];
  int   bestK[4];
  #pragma unroll
  for (int r = 0; r < 4; ++r) { bestS[r] = -3.402823466e38f; bestK[r] = 0x7FFFFFFF; }

#define VMWAIT2                                                \
  do {                                                         \
    asm volatile("s_waitcnt vmcnt(2)" ::: "memory");           \
    __builtin_amdgcn_sched_barrier(0);                         \
  } while (0)

  // 16 groups. Steady state: own 2 loads of g(m+1) in flight; VMWAIT(2) ->
  // own g(m) chunk landed; barrier -> ALL waves' chunks landed -> 16 KB
  // group complete. Stage g(m+2) into slot of g(m-1): its reads were
  // data-consumed (lgkmcnt before MFMA use) before the barrier -> safe.
  // Wrap-staging (m=14,15 restage g0,g1 into dead slots) keeps vmcnt uniform.
  int sCur = 0, sStg = 2;
  #pragma unroll 1
  for (int m = 0; m < 16; ++m) {
    VMWAIT2;
    __builtin_amdgcn_s_barrier();
    STAGEG(m + 2, sStg);
    const int gi = (pg + m) & 15;
    const unsigned short* gb = &ring[sCur][0];
    #pragma unroll
    for (int j = 0; j < 4; ++j) {
      const int tj  = gi * 4 + j;
      const int kk0 = tj * 16 + col;
      const unsigned short* sl = gb + j * 2048;
      uint4 u0 = *(const uint4*)(sl + 0 * 512 + l * 8);
      uint4 u1 = *(const uint4*)(sl + 1 * 512 + l * 8);
      uint4 u2 = *(const uint4*)(sl + 2 * 512 + l * 8);
      uint4 u3 = *(const uint4*)(sl + 3 * 512 + l * 8);
      const float ne2 = -e2L[kk0];
      U4H q0, q1, q2, q3; q0.u = u0; q1.u = u1; q2.u = u2; q3.u = u3;
      f32x4 c0 = {ne2, ne2, ne2, ne2};
      f32x4 c1 = {0.f, 0.f, 0.f, 0.f};
      c0 = __builtin_amdgcn_mfma_f32_16x16x32_f16(a[0][0], q0.h, c0, 0, 0, 0);
      c1 = __builtin_amdgcn_mfma_f32_16x16x32_f16(a[1][0], q2.h, c1, 0, 0, 0);
      c0 = __builtin_amdgcn_mfma_f32_16x16x32_f16(a[0][1], q0.h, c0, 0, 0, 0);
      c1 = __builtin_amdgcn_mfma_f32_16x16x32_f16(a[1][1], q2.h, c1, 0, 0, 0);
      c0 = __builtin_amdgcn_mfma_f32_16x16x32_f16(a[0][0], q1.h, c0, 0, 0, 0);
      c1 = __builtin_amdgcn_mfma_f32_16x16x32_f16(a[1][0], q3.h, c1, 0, 0, 0);
      #pragma unroll
      for (int r = 0; r < 4; ++r) {
        float sv = c0[r] + c1[r];
        bool take = (sv > bestS[r]) || (sv == bestS[r] && kk0 < bestK[r]);
        if (take) { bestS[r] = sv; bestK[r] = kk0; }
      }
    }
    sCur = (sCur == 2) ? 0 : sCur + 1;
    sStg = (sStg == 2) ? 0 : sStg + 1;
  }

  // ---- intra-wave argmax(S') merge over the 16 code-columns ----
  #pragma unroll
  for (int off = 1; off <= 8; off <<= 1) {
    #pragma unroll
    for (int r = 0; r < 4; ++r) {
      float sp = __shfl_xor(bestS[r], off, 64);
      int   kp = __shfl_xor(bestK[r], off, 64);
      if (sp > bestS[r] || (sp == bestS[r] && kp < bestK[r])) {
        bestS[r] = sp; bestK[r] = kp;
      }
    }
  }

  // col==0 lanes (g=0..3) hold FINAL minima for rows R0 + g*4 + r
  float ssum = 0.f;
  if (col == 0) {
    #pragma unroll
    for (int r = 0; r < 4; ++r) {
      kFin[wv * 16 + g * 4 + r] = bestK[r];
      ssum += bestS[r];
    }
  }
  ssum += __shfl_xor(ssum, 16, 64);
  ssum += __shfl_xor(ssum, 32, 64);
  if (l == 0)   // wave partial: Sum d(16 rows) = Sum x^2 - 2*Sum S'best
    lossP[wv] = fmaf(-2.f, ssum, x2p);

  __syncthreads();
  if (t == 0) {
    float bl = ((lossP[0] + lossP[1]) + (lossP[2] + lossP[3])) +
               ((lossP[4] + lossP[5]) + (lossP[6] + lossP[7]));
    atomicAdd(loss, bl * (1.25f / (float)((size_t)NROWS * DIM)));
  }

  // ---- cooperative gather-write: 4 threads/row, 16 floats each ----
  {
    const int row = t >> 2, seg = t & 3;
    const int bk = kFin[row];
    const float4* src = (const float4*)(e + (size_t)bk * DIM + seg * 16);
    float4* dst = (float4*)(out + (size_t)(B0 + row) * DIM + seg * 16);
    #pragma unroll
    for (int i = 0; i < 4; ++i) dst[i] = src[i];
  }
}

extern "C" void kernel_launch(void* const* d_in, const int* in_sizes, int n_in,
                              void* d_out, int out_size, void* d_ws, size_t ws_size,
                              hipStream_t stream) {
  const float* x = (const float*)d_in[0];   // [65536, 64]
  const float* e = (const float*)d_in[1];   // [1024, 64]
  float* out  = (float*)d_out;              // quantized_st [65536*64] + loss [1]
  float* loss = out + (size_t)NROWS * DIM;

  unsigned short* eB = (unsigned short*)d_ws;            // 64 tiles * 4 KB = 256 KB
  float* e2h = (float*)((char*)d_ws + 64 * 2048 * 2);    // 4 KB

  vq_esplit<<<NCODE / 256, 256, 0, stream>>>(e, eB, e2h, loss);
  vq_main  <<<NBLK, 512, 0, stream>>>(x, e, eB, e2h, out, loss);
}